// Round 11
// baseline (40.004 us; speedup 1.0000x reference)
//
#include <hip/hip_runtime.h>
#include <math.h>

#define BLK 100          // BLOCK
#define NF  128          // N_freqs
#define NTOT (NF * BLK)  // 12800
#define P   104          // LDS pitch (floats): rows 16B-aligned (416B)
#define NT  512          // 8 waves = 2 waves/SIMD (measured best: R7 vs R6/R10)

__device__ __forceinline__ float4 fnma4(float4 v, float s, const float4 p) {
    v.x -= s * p.x; v.y -= s * p.y; v.z -= s * p.z; v.w -= s * p.w; return v;
}

__device__ __forceinline__ float rdl(float x, int l) {
    return __uint_as_float(__builtin_amdgcn_readlane(__float_as_uint(x), l));
}

#define LD4(r, c4) (*reinterpret_cast<float4*>(&a[(r) * P + 4 * (c4)]))

// One workgroup (512 thr) per frequency block. Rank-4 blocked non-pivoted LU
// in LDS, ONE barrier per phase. Panel handling: each wave reads only the 4
// per-lane pivot-row vectors P0..P3; the panel column group pp0..pp3 is
// EXTRACTED from P via v_readlane at lane gp (lanes 0-31 and 32-63 mirror
// the same data, so one readlane per component suffices -> SGPR broadcast).
// This removes the 4 uniform LDS reads per wave per phase (-24% LDS instrs).
// Every lane then redundantly factors the 4x4 panel in registers.
__global__ __launch_bounds__(NT) void lu_logdet_kernel(const float* __restrict__ w,
                                                       const float* __restrict__ L,
                                                       float* __restrict__ out) {
    __shared__ float a[BLK * P];
    __shared__ float diag[BLK];
    __shared__ float ps[2];
    __shared__ int   pn[2];

    const int f   = blockIdx.x;
    const int tid = threadIdx.x;
    const int sid = tid >> 5;        // 16 half-wave streams
    const int g   = tid & 31;        // float4 column group
    const int gg  = (g < 25) ? g : 24;   // clamped, keeps inactive lanes in-bounds

    // ---- load diag block f, fused transform: M[r][c] = s_r*D[r][c] + (r==c ? 1-s_r : 0)
    const float* base = L + (size_t)f * BLK * NTOT + (size_t)f * BLK;
    for (int q = tid; q < BLK * 25; q += NT) {         // 25 float4 per row
        const int r  = q / 25;
        const int c0 = (q - r * 25) * 4;
        const float4 v = *reinterpret_cast<const float4*>(base + (size_t)r * NTOT + c0);
        const float sv = 1.0f / (1.0f + expf(-w[f * BLK + r]));
        const float ds = 1.0f - sv;
        float4 m;
        m.x = sv * v.x + ((c0 + 0) == r ? ds : 0.0f);
        m.y = sv * v.y + ((c0 + 1) == r ? ds : 0.0f);
        m.z = sv * v.z + ((c0 + 2) == r ? ds : 0.0f);
        m.w = sv * v.w + ((c0 + 3) == r ? ds : 0.0f);
        *reinterpret_cast<float4*>(&a[r * P + c0]) = m;
    }
    __syncthreads();

    for (int k0 = 0; k0 < BLK; k0 += 4) {
        const int gp = k0 >> 2;

        // ---- per-lane pivot-row reads (the only panel LDS traffic)
        float4 P0 = LD4(k0 + 0, gg);
        float4 P1 = LD4(k0 + 1, gg);
        float4 P2 = LD4(k0 + 2, gg);
        float4 P3 = LD4(k0 + 3, gg);

        // ---- pp = panel column group, extracted from P at lane gp (mirrored halves)
        float4 pp0 = make_float4(rdl(P0.x, gp), rdl(P0.y, gp), rdl(P0.z, gp), rdl(P0.w, gp));
        float4 pp1 = make_float4(rdl(P1.x, gp), rdl(P1.y, gp), rdl(P1.z, gp), rdl(P1.w, gp));
        float4 pp2 = make_float4(rdl(P2.x, gp), rdl(P2.y, gp), rdl(P2.z, gp), rdl(P2.w, gp));
        float4 pp3 = make_float4(rdl(P3.x, gp), rdl(P3.y, gp), rdl(P3.z, gp), rdl(P3.w, gp));

        // ---- redundant in-register 4x4 panel factorization (no cross-lane ops)
        const float d0 = pp0.x, r0i = 1.0f / d0;
        float fc;
        fc = pp1.x * r0i;  pp1 = fnma4(pp1, fc, pp0);  P1 = fnma4(P1, fc, P0);
        const float d1 = pp1.y, r1i = 1.0f / d1;
        fc = pp2.x * r0i;  pp2 = fnma4(pp2, fc, pp0);  P2 = fnma4(P2, fc, P0);
        fc = pp2.y * r1i;  pp2 = fnma4(pp2, fc, pp1);  P2 = fnma4(P2, fc, P1);
        const float d2 = pp2.z, r2i = 1.0f / d2;
        fc = pp3.x * r0i;  pp3 = fnma4(pp3, fc, pp0);  P3 = fnma4(P3, fc, P0);
        fc = pp3.y * r1i;  pp3 = fnma4(pp3, fc, pp1);  P3 = fnma4(P3, fc, P1);
        fc = pp3.z * r2i;  pp3 = fnma4(pp3, fc, pp2);  P3 = fnma4(P3, fc, P2);
        const float d3 = pp3.w, r3i = 1.0f / d3;

        if (tid == 0) {
            diag[k0 + 0] = d0; diag[k0 + 1] = d1;
            diag[k0 + 2] = d2; diag[k0 + 3] = d3;
        }

        // ---- sweep: rank-4 update of rows k0+4..99, 16 streams, groups > gp
#define FACS(pan, f0, f1, f2, f3)                                             \
        const float f0 = pan.x * r0i;                                         \
        const float f1 = (pan.y - f0 * pp0.y) * r1i;                          \
        const float f2 = (pan.z - f0 * pp0.z - f1 * pp1.z) * r2i;             \
        const float f3 = (pan.w - f0 * pp0.w - f1 * pp1.w - f2 * pp2.w) * r3i;

        if (g > gp && g < 25) {
            int i = k0 + 4 + sid;
            for (; i + 16 < BLK; i += 32) {
                const int i2 = i + 16;
                const float4 panA = LD4(i,  gp);
                const float4 panB = LD4(i2, gp);
                float4 vA = LD4(i,  g);
                float4 vB = LD4(i2, g);
                FACS(panA, a0, a1, a2, a3)
                FACS(panB, b0, b1, b2, b3)
                vA = fnma4(vA, a0, P0); vA = fnma4(vA, a1, P1);
                vA = fnma4(vA, a2, P2); vA = fnma4(vA, a3, P3);
                vB = fnma4(vB, b0, P0); vB = fnma4(vB, b1, P1);
                vB = fnma4(vB, b2, P2); vB = fnma4(vB, b3, P3);
                LD4(i,  g) = vA;
                LD4(i2, g) = vB;
            }
            for (; i < BLK; i += 16) {
                const float4 pan = LD4(i, gp);
                float4 v = LD4(i, g);
                FACS(pan, c0, c1, c2, c3)
                v = fnma4(v, c0, P0); v = fnma4(v, c1, P1);
                v = fnma4(v, c2, P2); v = fnma4(v, c3, P3);
                LD4(i, g) = v;
            }
        }
#undef FACS
        __syncthreads();
    }

    // ---- epilogue: parallel logf over diag, shuffle reduce (waves 0-1 only)
    float lsum = 0.0f;
    int   lneg = 0;
    if (tid < BLK) {
        const float d = diag[tid];
        lsum = logf(fabsf(d));                   // d==0 -> -inf -> caught below
        lneg = (d < 0.0f) ? 1 : 0;
    }
    if (tid < 128) {
        for (int off = 32; off > 0; off >>= 1) {
            lsum += __shfl_down(lsum, off);
            lneg += __shfl_down(lneg, off);
        }
        if ((tid & 63) == 0) { ps[tid >> 6] = lsum; pn[tid >> 6] = lneg; }
    }
    __syncthreads();
    if (tid == 0) {
        float ld = ps[0] + ps[1];
        const int n = pn[0] + pn[1];
        if ((n & 1) || !isfinite(ld)) ld = __int_as_float(0x7fc00000);  // NaN
        out[1 + f] = ld;
        atomicAdd(out, ld);   // out[0] zeroed via memset before launch; NaN propagates
    }
}

extern "C" void kernel_launch(void* const* d_in, const int* in_sizes, int n_in,
                              void* d_out, int out_size, void* d_ws, size_t ws_size,
                              hipStream_t stream) {
    const float* w = (const float*)d_in[0];   // weights (12800,) f32
    const float* L = (const float*)d_in[1];   // L_kernel (12800,12800) f32
    float* out = (float*)d_out;               // [0]=sum, [1..128]=logdets
    hipMemsetAsync(d_out, 0, sizeof(float), stream);   // zero the atomic accumulator
    lu_logdet_kernel<<<NF, NT, 0, stream>>>(w, L, out);
}

// Round 12
// 36.526 us; speedup vs baseline: 1.0952x; 1.0952x over previous
//
#include <hip/hip_runtime.h>
#include <math.h>

#define BLK 100          // BLOCK
#define NF  128          // N_freqs
#define NTOT (NF * BLK)  // 12800
#define P   104          // LDS pitch (floats): rows 16B-aligned (416B)
#define NT  512          // 8 waves = 2 waves/SIMD (measured best: R7 vs R6/R10/R11)

__device__ __forceinline__ float4 fnma4(float4 v, float s, const float4 p) {
    v.x -= s * p.x; v.y -= s * p.y; v.z -= s * p.z; v.w -= s * p.w; return v;
}
__device__ __forceinline__ float4 mul4(float4 v, float s) {
    v.x *= s; v.y *= s; v.z *= s; v.w *= s; return v;
}

#define LD4(r, c4) (*reinterpret_cast<float4*>(&a[(r) * P + 4 * (c4)]))

// One workgroup (512 thr) per frequency block. Rank-4 blocked non-pivoted LU
// in LDS, ONE barrier per phase. Per phase, each lane:
//   - reads pp0..3 (uniform broadcast) + P0..3 (per-lane) pivot-row data,
//   - redundantly factors the 4x4 panel (L,U) and applies the L-forward pass
//     to P (as in R7), then BACK-SUBSTITUTES to get Q = U^-1 L^-1 P_raw,
//   - sweep rows then need NO per-row triangular solve:
//       v -= pan.x*Q0 + pan.y*Q1 + pan.z*Q2 + pan.w*Q3   (chain depth 4)
// logdet accumulates per-thread as mantissa*2^e (frexpf); thread 0 publishes.
__global__ __launch_bounds__(NT) void lu_logdet_kernel(const float* __restrict__ w,
                                                       const float* __restrict__ L,
                                                       float* __restrict__ out) {
    __shared__ float a[BLK * P];

    const int f   = blockIdx.x;
    const int tid = threadIdx.x;
    const int sid = tid >> 5;        // 16 half-wave streams
    const int g   = tid & 31;        // float4 column group
    const int gg  = (g < 25) ? g : 24;   // clamped, keeps inactive lanes in-bounds

    // ---- load diag block f, fused transform: M[r][c] = s_r*D[r][c] + (r==c ? 1-s_r : 0)
    const float* base = L + (size_t)f * BLK * NTOT + (size_t)f * BLK;
    for (int q = tid; q < BLK * 25; q += NT) {         // 25 float4 per row
        const int r  = q / 25;
        const int c0 = (q - r * 25) * 4;
        const float4 v = *reinterpret_cast<const float4*>(base + (size_t)r * NTOT + c0);
        const float sv = 1.0f / (1.0f + expf(-w[f * BLK + r]));
        const float ds = 1.0f - sv;
        float4 m;
        m.x = sv * v.x + ((c0 + 0) == r ? ds : 0.0f);
        m.y = sv * v.y + ((c0 + 1) == r ? ds : 0.0f);
        m.z = sv * v.z + ((c0 + 2) == r ? ds : 0.0f);
        m.w = sv * v.w + ((c0 + 3) == r ? ds : 0.0f);
        *reinterpret_cast<float4*>(&a[r * P + c0]) = m;
    }
    __syncthreads();

    float mant = 1.0f;   // running product mantissa (frexp-normalized)
    int   e2   = 0;      // running exponent
    int   lneg = 0;      // count of negative diagonal entries

    for (int k0 = 0; k0 < BLK; k0 += 4) {
        const int gp = k0 >> 2;

        // ---- panel in: 4 uniform (broadcast) + 4 per-lane LDS reads
        float4 pp0 = LD4(k0 + 0, gp);
        float4 pp1 = LD4(k0 + 1, gp);
        float4 pp2 = LD4(k0 + 2, gp);
        float4 pp3 = LD4(k0 + 3, gp);
        float4 P0  = LD4(k0 + 0, gg);
        float4 P1  = LD4(k0 + 1, gg);
        float4 P2  = LD4(k0 + 2, gg);
        float4 P3  = LD4(k0 + 3, gg);

        // ---- redundant 4x4 panel factorization + L-forward pass on P
        const float d0 = pp0.x, r0i = 1.0f / d0;
        float l;
        l = pp1.x * r0i;  pp1 = fnma4(pp1, l, pp0);  P1 = fnma4(P1, l, P0);
        const float d1 = pp1.y, r1i = 1.0f / d1;
        l = pp2.x * r0i;  pp2 = fnma4(pp2, l, pp0);  P2 = fnma4(P2, l, P0);
        l = pp2.y * r1i;  pp2 = fnma4(pp2, l, pp1);  P2 = fnma4(P2, l, P1);
        const float d2 = pp2.z, r2i = 1.0f / d2;
        l = pp3.x * r0i;  pp3 = fnma4(pp3, l, pp0);  P3 = fnma4(P3, l, P0);
        l = pp3.y * r1i;  pp3 = fnma4(pp3, l, pp1);  P3 = fnma4(P3, l, P1);
        l = pp3.z * r2i;  pp3 = fnma4(pp3, l, pp2);  P3 = fnma4(P3, l, P2);
        const float d3 = pp3.w, r3i = 1.0f / d3;

        // ---- back-substitute: Q = U^-1 (L^-1 P)  -> per-row solve vanishes
        const float4 Q3 = mul4(P3, r3i);
        const float4 Q2 = mul4(fnma4(P2, pp2.w, Q3), r2i);
        const float4 Q1 = mul4(fnma4(fnma4(P1, pp1.z, Q2), pp1.w, Q3), r1i);
        const float4 Q0 = mul4(fnma4(fnma4(fnma4(P0, pp0.y, Q1), pp0.z, Q2), pp0.w, Q3), r0i);

        // ---- accumulate log-magnitude as normalized product + exponent
        mant *= d0 * d1 * d2 * d3;
        { int t; mant = frexpf(mant, &t); e2 += t; }
        lneg += (d0 < 0.0f) + (d1 < 0.0f) + (d2 < 0.0f) + (d3 < 0.0f);

        // ---- sweep: rows k0+4..99, 16 streams, groups > gp; 4 fnma4/row
        if (g > gp && g < 25) {
            int i = k0 + 4 + sid;
            for (; i + 16 < BLK; i += 32) {
                const int i2 = i + 16;
                const float4 panA = LD4(i,  gp);   // uniform per half-wave
                const float4 panB = LD4(i2, gp);
                float4 vA = LD4(i,  g);
                float4 vB = LD4(i2, g);
                vA = fnma4(vA, panA.x, Q0); vA = fnma4(vA, panA.y, Q1);
                vA = fnma4(vA, panA.z, Q2); vA = fnma4(vA, panA.w, Q3);
                vB = fnma4(vB, panB.x, Q0); vB = fnma4(vB, panB.y, Q1);
                vB = fnma4(vB, panB.z, Q2); vB = fnma4(vB, panB.w, Q3);
                LD4(i,  g) = vA;
                LD4(i2, g) = vB;
            }
            for (; i < BLK; i += 16) {
                const float4 pan = LD4(i, gp);
                float4 v = LD4(i, g);
                v = fnma4(v, pan.x, Q0); v = fnma4(v, pan.y, Q1);
                v = fnma4(v, pan.z, Q2); v = fnma4(v, pan.w, Q3);
                LD4(i, g) = v;
            }
        }
        __syncthreads();
    }

    // ---- every thread holds the full result redundantly; thread 0 publishes
    if (tid == 0) {
        float ld = logf(mant) + (float)e2 * 0.69314718055994531f;
        if ((lneg & 1) || !isfinite(ld)) ld = __int_as_float(0x7fc00000);  // NaN
        out[1 + f] = ld;
        atomicAdd(out, ld);   // out[0] zeroed via memset before launch; NaN propagates
    }
}

extern "C" void kernel_launch(void* const* d_in, const int* in_sizes, int n_in,
                              void* d_out, int out_size, void* d_ws, size_t ws_size,
                              hipStream_t stream) {
    const float* w = (const float*)d_in[0];   // weights (12800,) f32
    const float* L = (const float*)d_in[1];   // L_kernel (12800,12800) f32
    float* out = (float*)d_out;               // [0]=sum, [1..128]=logdets
    hipMemsetAsync(d_out, 0, sizeof(float), stream);   // zero the atomic accumulator
    lu_logdet_kernel<<<NF, NT, 0, stream>>>(w, L, out);
}

// Round 13
// 30.426 us; speedup vs baseline: 1.3148x; 1.2005x over previous
//
#include <hip/hip_runtime.h>
#include <math.h>

#define BLK 100          // BLOCK
#define NF  128          // N_freqs
#define NTOT (NF * BLK)  // 12800
#define P   104          // LDS pitch (floats): rows 16B-aligned (416B)
#define NT  512          // 8 waves = 2 waves/SIMD (measured best)

__device__ __forceinline__ float4 fnma4(float4 v, float s, const float4 p) {
    v.x -= s * p.x; v.y -= s * p.y; v.z -= s * p.z; v.w -= s * p.w; return v;
}
__device__ __forceinline__ float4 mul4(float4 v, float s) {
    v.x *= s; v.y *= s; v.z *= s; v.w *= s; return v;
}

#define LD4(r, c4) (*reinterpret_cast<float4*>(&a[(r) * P + 4 * (c4)]))

// Factor 4x4 panel at rows kb..kb+3 (panel col group gq), lane col group gg.
// Outputs Q = U^-1 L^-1 P_raw and the 4 diag values. Pure per-lane ops.
#define PANEL_Q(kb, gq)                                                        \
    {                                                                          \
        float4 pp0 = LD4((kb) + 0, (gq));                                      \
        float4 pp1 = LD4((kb) + 1, (gq));                                      \
        float4 pp2 = LD4((kb) + 2, (gq));                                      \
        float4 pp3 = LD4((kb) + 3, (gq));                                      \
        float4 P0  = LD4((kb) + 0, gg);                                        \
        float4 P1  = LD4((kb) + 1, gg);                                        \
        float4 P2  = LD4((kb) + 2, gg);                                        \
        float4 P3  = LD4((kb) + 3, gg);                                        \
        const float d0 = pp0.x, r0i = 1.0f / d0;                               \
        float l;                                                               \
        l = pp1.x * r0i;  pp1 = fnma4(pp1, l, pp0);  P1 = fnma4(P1, l, P0);    \
        const float d1 = pp1.y, r1i = 1.0f / d1;                               \
        l = pp2.x * r0i;  pp2 = fnma4(pp2, l, pp0);  P2 = fnma4(P2, l, P0);    \
        l = pp2.y * r1i;  pp2 = fnma4(pp2, l, pp1);  P2 = fnma4(P2, l, P1);    \
        const float d2 = pp2.z, r2i = 1.0f / d2;                               \
        l = pp3.x * r0i;  pp3 = fnma4(pp3, l, pp0);  P3 = fnma4(P3, l, P0);    \
        l = pp3.y * r1i;  pp3 = fnma4(pp3, l, pp1);  P3 = fnma4(P3, l, P1);    \
        l = pp3.z * r2i;  pp3 = fnma4(pp3, l, pp2);  P3 = fnma4(P3, l, P2);    \
        const float d3 = pp3.w, r3i = 1.0f / d3;                               \
        Q3 = mul4(P3, r3i);                                                    \
        Q2 = mul4(fnma4(P2, pp2.w, Q3), r2i);                                  \
        Q1 = mul4(fnma4(fnma4(P1, pp1.z, Q2), pp1.w, Q3), r1i);                \
        Q0 = mul4(fnma4(fnma4(fnma4(P0, pp0.y, Q1), pp0.z, Q2), pp0.w, Q3), r0i); \
        mant *= d0 * d1 * d2 * d3;                                             \
        { int t_; mant = frexpf(mant, &t_); e2 += t_; }                        \
        lneg += (d0 < 0.0f) + (d1 < 0.0f) + (d2 < 0.0f) + (d3 < 0.0f);         \
    }

// One workgroup (512 thr) per frequency block. Rank-4 blocked non-pivoted LU
// in LDS, 1 barrier/phase, PRODUCER/CONSUMER split:
//   wave 0 (producer): urgent-sweep rows k0+4..7 with Q(k0), factor
//     panel(k0+4), back-substitute -> Q(k0+4), publish to qbuf (dbuffered),
//     track mant/e2/lneg redundantly in its lanes. setprio(1) while producing.
//   waves 1-7 (consumers): load Q(k0) (4 per-lane b128 -- replaces the
//     8 panel reads + ~250-cyc chain), bulk-sweep rows k0+8..99, 14 streams.
// Prologue: ALL waves redundantly compute Q(0) (no qbuf read at k0=0).
__global__ __launch_bounds__(NT) void lu_logdet_kernel(const float* __restrict__ w,
                                                       const float* __restrict__ L,
                                                       float* __restrict__ out) {
    __shared__ float  a[BLK * P];
    __shared__ float4 qbuf[2][4][26];

    const int f    = blockIdx.x;
    const int tid  = threadIdx.x;
    const int wave = tid >> 6;
    const int sid  = tid >> 5;       // 16 half-wave streams
    const int g    = tid & 31;       // float4 column group
    const int gg   = (g < 25) ? g : 24;

    // ---- load diag block f, fused transform: M[r][c] = s_r*D[r][c] + (r==c ? 1-s_r : 0)
    const float* base = L + (size_t)f * BLK * NTOT + (size_t)f * BLK;
    for (int q = tid; q < BLK * 25; q += NT) {         // 25 float4 per row
        const int r  = q / 25;
        const int c0 = (q - r * 25) * 4;
        const float4 v = *reinterpret_cast<const float4*>(base + (size_t)r * NTOT + c0);
        const float sv = 1.0f / (1.0f + expf(-w[f * BLK + r]));
        const float ds = 1.0f - sv;
        float4 m;
        m.x = sv * v.x + ((c0 + 0) == r ? ds : 0.0f);
        m.y = sv * v.y + ((c0 + 1) == r ? ds : 0.0f);
        m.z = sv * v.z + ((c0 + 2) == r ? ds : 0.0f);
        m.w = sv * v.w + ((c0 + 3) == r ? ds : 0.0f);
        *reinterpret_cast<float4*>(&a[r * P + c0]) = m;
    }
    __syncthreads();

    float mant = 1.0f;   // running product mantissa (frexp-normalized)
    int   e2   = 0;      // running exponent
    int   lneg = 0;      // negative-diagonal count
    float4 Q0, Q1, Q2, Q3;

    // ---- prologue: everyone computes Q(0) redundantly (all need it at k0=0)
    PANEL_Q(0, 0)

    for (int k0 = 0; k0 <= 92; k0 += 4) {
        const int gp = k0 >> 2;
        const int b  = gp & 1;
        const int nb = b ^ 1;

        if (wave == 0) {
            __builtin_amdgcn_s_setprio(1);
            // ---- urgent sweep of next panel rows k0+4..k0+7 (2 streams x 2 rows)
            if (g > gp && g < 25) {
                const int s  = sid & 1;
                const int i1 = k0 + 4 + s;
                const int i2 = k0 + 6 + s;
                const float4 pan1 = LD4(i1, gp);
                const float4 pan2 = LD4(i2, gp);
                float4 v1 = LD4(i1, g);
                float4 v2 = LD4(i2, g);
                v1 = fnma4(v1, pan1.x, Q0); v1 = fnma4(v1, pan1.y, Q1);
                v1 = fnma4(v1, pan1.z, Q2); v1 = fnma4(v1, pan1.w, Q3);
                v2 = fnma4(v2, pan2.x, Q0); v2 = fnma4(v2, pan2.y, Q1);
                v2 = fnma4(v2, pan2.z, Q2); v2 = fnma4(v2, pan2.w, Q3);
                LD4(i1, g) = v1;
                LD4(i2, g) = v2;
            }
            // ---- factor panel(k0+4) (rows just swept by THIS wave; DS in-order)
            PANEL_Q(k0 + 4, gp + 1)
            if (g < 25) {
                qbuf[nb][0][g] = Q0; qbuf[nb][1][g] = Q1;
                qbuf[nb][2][g] = Q2; qbuf[nb][3][g] = Q3;
            }
            __builtin_amdgcn_s_setprio(0);
        } else {
            // ---- consumers: fetch Q(k0) (prologue regs at k0==0), bulk sweep
            if (k0 > 0) {
                Q0 = qbuf[b][0][gg]; Q1 = qbuf[b][1][gg];
                Q2 = qbuf[b][2][gg]; Q3 = qbuf[b][3][gg];
            }
            if (g > gp && g < 25) {
                int i = k0 + 8 + (sid - 2);      // 14 streams
                for (; i + 14 < BLK; i += 28) {
                    const int i2 = i + 14;
                    const float4 panA = LD4(i,  gp);
                    const float4 panB = LD4(i2, gp);
                    float4 vA = LD4(i,  g);
                    float4 vB = LD4(i2, g);
                    vA = fnma4(vA, panA.x, Q0); vA = fnma4(vA, panA.y, Q1);
                    vA = fnma4(vA, panA.z, Q2); vA = fnma4(vA, panA.w, Q3);
                    vB = fnma4(vB, panB.x, Q0); vB = fnma4(vB, panB.y, Q1);
                    vB = fnma4(vB, panB.z, Q2); vB = fnma4(vB, panB.w, Q3);
                    LD4(i,  g) = vA;
                    LD4(i2, g) = vB;
                }
                for (; i < BLK; i += 14) {
                    const float4 pan = LD4(i, gp);
                    float4 v = LD4(i, g);
                    v = fnma4(v, pan.x, Q0); v = fnma4(v, pan.y, Q1);
                    v = fnma4(v, pan.z, Q2); v = fnma4(v, pan.w, Q3);
                    LD4(i, g) = v;
                }
            }
        }
        __syncthreads();
    }

    // ---- wave 0 lanes hold the full result redundantly; thread 0 publishes
    if (tid == 0) {
        float ld = logf(mant) + (float)e2 * 0.69314718055994531f;
        if ((lneg & 1) || !isfinite(ld)) ld = __int_as_float(0x7fc00000);  // NaN
        out[1 + f] = ld;
        atomicAdd(out, ld);   // out[0] zeroed via memset before launch; NaN propagates
    }
}

extern "C" void kernel_launch(void* const* d_in, const int* in_sizes, int n_in,
                              void* d_out, int out_size, void* d_ws, size_t ws_size,
                              hipStream_t stream) {
    const float* w = (const float*)d_in[0];   // weights (12800,) f32
    const float* L = (const float*)d_in[1];   // L_kernel (12800,12800) f32
    float* out = (float*)d_out;               // [0]=sum, [1..128]=logdets
    hipMemsetAsync(d_out, 0, sizeof(float), stream);   // zero the atomic accumulator
    lu_logdet_kernel<<<NF, NT, 0, stream>>>(w, L, out);
}